// Round 1
// 1031.263 us; speedup vs baseline: 1.8770x; 1.8770x over previous
//
#include <hip/hip_runtime.h>
#include <math.h>

#define B_   64
#define C_   2048
#define M_   64
#define P_   1000
#define NC_  100
#define NPR_ 10

// d_out offsets (in floats), concatenated tuple return order
#define OUT_OFF      0
#define CONTRIB_OFF  6400
#define SIMR_OFF     70400
#define COSV_OFF     134400
#define COSD_OFF     4230400
#define MAXFS_OFF    8326400
#define ARGMAX_OFF   139398400

// workspace offsets (in floats / 4-byte units)
#define A_OFF     0            // f/na rows: [B*M][C]  (8,388,608 floats)
#define NA_OFF    8388608      // na per (b,m): [4096]
#define BM_OFF    8392704      // proto/n1/nb: [C][P]  (2,048,000 floats)
#define AI_OFF    10440704     // argmax int: [B*P] (64,000)
#define PART_OFF  10504704     // proto partial ss: [64 chunks][1024 p] (65,536)
#define SCALE_OFF 10570240     // proto combined scale: [1024]

#define PCH     32             // c-rows per partial-sum block
#define NCHUNK  (C_ / PCH)     // 64

// ---------------------------------------------------------------- kernel A
// pool 16x16 -> 8x8 (2x2 mean), l2-normalize over C, store (f/na) and na.
__global__ __launch_bounds__(256) void pool_norm_kernel(
    const float* __restrict__ x, float* __restrict__ ws) {
  int bm = blockIdx.x;            // b*64 + m
  int b = bm >> 6, m = bm & 63;
  int mh = m >> 3, mw = m & 7;
  int tid = threadIdx.x;
  __shared__ float sred1[4];
  __shared__ float sred2[4];

  float pooled[8];
  float ss = 0.f;
  int hw = (2 * mh) * 16 + 2 * mw;
  #pragma unroll
  for (int i = 0; i < 8; i++) {
    int c = tid + i * 256;
    const float* px = x + (size_t)(b * C_ + c) * 256 + hw;
    float2 a0 = *(const float2*)px;
    float2 a1 = *(const float2*)(px + 16);
    float v = ((a0.x + a0.y) + (a1.x + a1.y)) * 0.25f;
    pooled[i] = v;
    ss += v * v;
  }
  // block reduction (sum) of ss
  #pragma unroll
  for (int off = 32; off >= 1; off >>= 1) ss += __shfl_xor(ss, off, 64);
  if ((tid & 63) == 0) sred1[tid >> 6] = ss;
  __syncthreads();
  float tot = sred1[0] + sred1[1] + sred1[2] + sred1[3];
  float n1 = fmaxf(sqrtf(tot), 1e-12f);

  float fn[8];
  float ss2 = 0.f;
  #pragma unroll
  for (int i = 0; i < 8; i++) {
    fn[i] = pooled[i] / n1;
    ss2 += fn[i] * fn[i];
  }
  #pragma unroll
  for (int off = 32; off >= 1; off >>= 1) ss2 += __shfl_xor(ss2, off, 64);
  if ((tid & 63) == 0) sred2[tid >> 6] = ss2;
  __syncthreads();
  float tot2 = sred2[0] + sred2[1] + sred2[2] + sred2[3];
  float na = sqrtf(tot2) + 1e-3f;

  #pragma unroll
  for (int i = 0; i < 8; i++) {
    int c = tid + i * 256;
    ws[A_OFF + (size_t)bm * C_ + c] = fn[i] / na;
  }
  if (tid == 0) ws[NA_OFF + bm] = na;
}

// ---------------------------------------------------------------- kernel B1
// partial sum of squares per prototype column. grid (4, NCHUNK), block 256.
// Coalesced: consecutive threads -> consecutive p.
__global__ __launch_bounds__(256) void proto_ss_kernel(
    const float* __restrict__ proto, float* __restrict__ ws) {
  int p = blockIdx.x * 256 + threadIdx.x;   // 0..1023
  int c0 = blockIdx.y * PCH;
  float ss = 0.f;
  if (p < P_) {
    const float* pp = proto + (size_t)c0 * P_ + p;
    #pragma unroll
    for (int i = 0; i < PCH; i++) {
      float v = pp[(size_t)i * P_];
      ss += v * v;
    }
  }
  ws[PART_OFF + blockIdx.y * 1024 + blockIdx.x * 256 + threadIdx.x] = ss;
}

// ---------------------------------------------------------------- kernel B2
// reduce partials, fold both normalizations into one per-column scale.
// ss2 = ss / n1^2  =>  nb = sqrt(ss)/n1 + 1e-3 ; scale = 1/(n1*nb).
__global__ __launch_bounds__(256) void proto_scale_kernel(
    float* __restrict__ ws) {
  int p = blockIdx.x * 256 + threadIdx.x;   // grid 4
  if (p >= 1024) return;
  float ss = 0.f;
  #pragma unroll 8
  for (int j = 0; j < NCHUNK; j++) ss += ws[PART_OFF + j * 1024 + p];
  float sr = sqrtf(ss);
  float n1 = fmaxf(sr, 1e-12f);
  float nb = sr / n1 + 1e-3f;
  ws[SCALE_OFF + p] = 1.f / (n1 * nb);
}

// ---------------------------------------------------------------- kernel B3
// BM[c][p] = proto[c][p] * scale[p], float4-vectorized. grid C_, block 256.
__global__ __launch_bounds__(256) void proto_apply_kernel(
    const float* __restrict__ proto, float* __restrict__ ws) {
  int c = blockIdx.x;
  int t = threadIdx.x;
  if (t >= P_ / 4) return;                  // 250 active threads
  size_t off = (size_t)c * P_ + t * 4;
  float4 v = *(const float4*)(proto + off);
  int p4 = t * 4;
  v.x *= ws[SCALE_OFF + p4 + 0];
  v.y *= ws[SCALE_OFF + p4 + 1];
  v.z *= ws[SCALE_OFF + p4 + 2];
  v.w *= ws[SCALE_OFF + p4 + 3];
  *(float4*)(ws + BM_OFF + off) = v;
}

// ---------------------------------------------------------------- kernel C
// cossim GEMM: per block, one b and a 64-wide p tile, all 64 m.
// Writes cosvalue/cosdist [b][p][m], sim_r, contrib, argmax (float + int).
#define BKT 32
__global__ __launch_bounds__(256) void gemm_kernel(
    const float* __restrict__ ws, float* __restrict__ out,
    const float* __restrict__ weight, const float* __restrict__ weight_e,
    int* __restrict__ argmax_i) {
  __shared__ float As[BKT][68];   // [k][m], padded stride 68 (16B-aligned reads)
  __shared__ float Bs[BKT][64];   // [k][p]
  __shared__ float rmax[16][64];  // 16 ty-groups x 64 p-cols
  __shared__ int   ridx[16][64];

  int pt = blockIdx.x, b = blockIdx.y;
  int p0 = pt * 64;
  int t = threadIdx.x;
  int tx = t & 15, ty = t >> 4;   // tx -> p (4 cols), ty -> m (4 rows)

  const float* Am = ws + A_OFF + (size_t)(b * 64) * C_;
  const float* Bm = ws + BM_OFF;

  float acc[4][4] = {};

  for (int k0 = 0; k0 < C_; k0 += BKT) {
    #pragma unroll
    for (int q = 0; q < 2; q++) {
      int flat = q * 256 + t;           // 0..511
      int row = flat >> 3;              // m: 0..63
      int k4 = (flat & 7) * 4;          // k: 0..28
      float4 v = *(const float4*)(Am + (size_t)row * C_ + k0 + k4);
      As[k4 + 0][row] = v.x;
      As[k4 + 1][row] = v.y;
      As[k4 + 2][row] = v.z;
      As[k4 + 3][row] = v.w;
    }
    #pragma unroll
    for (int q = 0; q < 2; q++) {
      int kr = (t >> 4) + q * 16;       // k: 0..31
      int pc = (t & 15) * 4;            // p: 0..60
      int p = p0 + pc;
      float4 v = make_float4(0.f, 0.f, 0.f, 0.f);
      if (p < P_) v = *(const float4*)(Bm + (size_t)(k0 + kr) * P_ + p);
      *(float4*)&Bs[kr][pc] = v;
    }
    __syncthreads();
    #pragma unroll
    for (int kk = 0; kk < BKT; kk++) {
      float4 a4 = *(const float4*)&As[kk][ty * 4];
      float4 b4 = *(const float4*)&Bs[kk][tx * 4];
      float a[4] = {a4.x, a4.y, a4.z, a4.w};
      float bb[4] = {b4.x, b4.y, b4.z, b4.w};
      #pragma unroll
      for (int i = 0; i < 4; i++)
        #pragma unroll
        for (int j = 0; j < 4; j++)
          acc[i][j] = fmaf(a[i], bb[j], acc[i][j]);
    }
    __syncthreads();
  }

  // epilogue: cosvalue / cosdist writes (m-contiguous float4 per p)
  #pragma unroll
  for (int j = 0; j < 4; j++) {
    int p = p0 + tx * 4 + j;
    if (p < P_) {
      float4 cv = make_float4(acc[0][j], acc[1][j], acc[2][j], acc[3][j]);
      size_t o = (size_t)(b * P_ + p) * 64 + ty * 4;
      *(float4*)(out + COSV_OFF + o) = cv;
      float4 cd = make_float4(1.f - cv.x, 1.f - cv.y, 1.f - cv.z, 1.f - cv.w);
      *(float4*)(out + COSD_OFF + o) = cd;
    }
  }

  // per-p max/argmax over m (numpy tie-break: first max => smallest m)
  #pragma unroll
  for (int j = 0; j < 4; j++) {
    float lm = acc[0][j];
    int li = ty * 4;
    #pragma unroll
    for (int i = 1; i < 4; i++) {
      if (acc[i][j] > lm) { lm = acc[i][j]; li = ty * 4 + i; }
    }
    rmax[ty][tx * 4 + j] = lm;
    ridx[ty][tx * 4 + j] = li;
  }
  __syncthreads();
  if (t < 64) {
    int p = p0 + t;
    if (p < P_) {
      float best = rmax[0][t];
      int bi = ridx[0][t];
      #pragma unroll
      for (int r = 1; r < 16; r++) {
        if (rmax[r][t] > best) { best = rmax[r][t]; bi = ridx[r][t]; }
      }
      int bp = b * P_ + p;
      out[SIMR_OFF + bp] = best;
      out[ARGMAX_OFF + bp] = (float)bi;
      argmax_i[bp] = bi;
      float w = weight[p];
      float we = weight_e[p];
      float sg = 1.f / (1.f + expf(-we));
      out[CONTRIB_OFF + bp] = best * w * sg;
    }
  }
}

// ---------------------------------------------------------------- kernel D
__global__ __launch_bounds__(256) void out_kernel(float* __restrict__ out) {
  int i = blockIdx.x * 256 + threadIdx.x;
  if (i >= B_ * NC_) return;
  int b = i / NC_, nc = i % NC_;
  const float* cb = out + CONTRIB_OFF + (size_t)b * P_ + nc * NPR_;
  float s = 0.f;
  #pragma unroll
  for (int j = 0; j < NPR_; j++) s += cb[j];
  out[OUT_OFF + i] = s;
}

// ---------------------------------------------------------------- kernel E
// maxfs gather: out[b][p][:] = (f/na)[b][argmax] * na  (float4-coalesced)
__global__ __launch_bounds__(256) void maxfs_kernel(
    const float* __restrict__ ws, const int* __restrict__ argmax_i,
    float* __restrict__ out) {
  int p = blockIdx.x, b = blockIdx.y;
  int bp = b * P_ + p;
  int idx = argmax_i[bp];
  float na = ws[NA_OFF + b * 64 + idx];
  const float* src = ws + A_OFF + (size_t)(b * 64 + idx) * C_;
  float* dst = out + MAXFS_OFF + (size_t)bp * C_;
  int t = threadIdx.x;
  #pragma unroll
  for (int q = 0; q < 2; q++) {
    int c = (t + q * 256) * 4;
    float4 v = *(const float4*)(src + c);
    v.x *= na; v.y *= na; v.z *= na; v.w *= na;
    *(float4*)(dst + c) = v;
  }
}

extern "C" void kernel_launch(void* const* d_in, const int* in_sizes, int n_in,
                              void* d_out, int out_size, void* d_ws, size_t ws_size,
                              hipStream_t stream) {
  const float* x        = (const float*)d_in[0];
  const float* proto    = (const float*)d_in[1];
  const float* weight   = (const float*)d_in[2];
  const float* weight_e = (const float*)d_in[3];
  float* out = (float*)d_out;
  float* ws  = (float*)d_ws;
  int* argmax_i = ((int*)d_ws) + AI_OFF;

  pool_norm_kernel<<<B_ * M_, 256, 0, stream>>>(x, ws);
  proto_ss_kernel<<<dim3(4, NCHUNK), 256, 0, stream>>>(proto, ws);
  proto_scale_kernel<<<4, 256, 0, stream>>>(ws);
  proto_apply_kernel<<<C_, 256, 0, stream>>>(proto, ws);
  gemm_kernel<<<dim3(16, B_), 256, 0, stream>>>(ws, out, weight, weight_e, argmax_i);
  out_kernel<<<(B_ * NC_ + 255) / 256, 256, 0, stream>>>(out);
  maxfs_kernel<<<dim3(P_, B_), 256, 0, stream>>>(ws, argmax_i, out);
}